// Round 9
// baseline (646.125 us; speedup 1.0000x reference)
//
#include <hip/hip_runtime.h>
#include <hip/hip_cooperative_groups.h>

namespace cg = cooperative_groups;

#define NF 128

typedef __attribute__((ext_vector_type(8))) short short8;
typedef __attribute__((ext_vector_type(4))) float f32x4;

__device__ inline ushort f2bf(float f) {
    uint u = __float_as_uint(f);
    return (ushort)((u + 0x7FFFu + ((u >> 16) & 1u)) >> 16);  // RNE
}
__device__ inline float bf2f(ushort u) {
    return __uint_as_float(((uint)u) << 16);
}

// ---------------------------------------------------------------------------
// One cooperative kernel: zero cnt + bf16 prep | hist | partials | scan |
// apply | fill.  Grid must be co-resident (1024 blocks x 256 thr).
// Assumes n_nodes <= 65536 (nb <= 256).
__global__ __launch_bounds__(256) void csr_build_kernel(
    const int* __restrict__ src, const int* __restrict__ dst,
    int* __restrict__ cnt, int* __restrict__ rowptr, int* __restrict__ partials,
    int* __restrict__ edge_src, const float* __restrict__ x,
    const float* __restrict__ W1, const float* __restrict__ W2,
    ushort* __restrict__ xb, ushort* __restrict__ W1t, ushort* __restrict__ W2t,
    int n_nodes, int n_edges, int nb, int n8) {
    cg::grid_group grid = cg::this_grid();
    __shared__ int s[256];
    int t = threadIdx.x;
    int gid = blockIdx.x * 256 + t;
    int gstride = gridDim.x * 256;

    // phase 0: zero cnt + weight/x bf16 conversion (independent work)
    for (int i = gid; i < n_nodes; i += gstride) cnt[i] = 0;
    for (int i = gid; i < 128 * 128; i += gstride) {
        int k = i >> 7, n = i & 127;
        W1t[n * NF + k] = f2bf(W1[i]);
    }
    for (int i = gid; i < 128 * 64; i += gstride) {
        int k = i >> 6, n = i & 63;
        W2t[n * NF + k] = f2bf(W2[i]);
    }
    {
        const float4* in4 = reinterpret_cast<const float4*>(x);
        for (int i = gid; i < n8; i += gstride) {
            float4 v0 = in4[i * 2], v1 = in4[i * 2 + 1];
            short8 o;
            o[0] = (short)f2bf(v0.x); o[1] = (short)f2bf(v0.y);
            o[2] = (short)f2bf(v0.z); o[3] = (short)f2bf(v0.w);
            o[4] = (short)f2bf(v1.x); o[5] = (short)f2bf(v1.y);
            o[6] = (short)f2bf(v1.z); o[7] = (short)f2bf(v1.w);
            *reinterpret_cast<short8*>(&xb[i * 8]) = o;
        }
    }
    grid.sync();

    // phase 1: histogram
    for (int e = gid; e < n_edges; e += gstride) atomicAdd(&cnt[dst[e]], 1);
    grid.sync();

    // phase 2: per-chunk partial sums (chunk = 256 nodes, block b -> chunk b)
    if (blockIdx.x < (unsigned)nb) {
        int i = blockIdx.x * 256 + t;
        s[t] = (i < n_nodes) ? cnt[i] : 0;
        __syncthreads();
        for (int off = 128; off > 0; off >>= 1) {
            if (t < off) s[t] += s[t + off];
            __syncthreads();
        }
        if (t == 0) partials[blockIdx.x] = s[0];
    }
    grid.sync();

    // phase 3: block 0 scans partials -> exclusive prefix
    if (blockIdx.x == 0) {
        int v = (t < nb) ? partials[t] : 0;
        s[t] = v;
        __syncthreads();
        for (int off = 1; off < 256; off <<= 1) {
            int a = (t >= off) ? s[t - off] : 0;
            __syncthreads();
            s[t] += a;
            __syncthreads();
        }
        if (t < nb) partials[t] = s[t] - v;  // exclusive
    }
    grid.sync();

    // phase 4: apply — rowptr[i+1] = incl prefix, cnt[i] = excl (cursor)
    if (blockIdx.x < (unsigned)nb) {
        int i = blockIdx.x * 256 + t;
        int v = (i < n_nodes) ? cnt[i] : 0;
        s[t] = v;
        __syncthreads();
        for (int off = 1; off < 256; off <<= 1) {
            int a = (t >= off) ? s[t - off] : 0;
            __syncthreads();
            s[t] += a;
            __syncthreads();
        }
        int off0 = partials[blockIdx.x];
        if (i < n_nodes) {
            rowptr[i + 1] = off0 + s[t];
            cnt[i] = off0 + s[t] - v;
        }
        if (blockIdx.x == 0 && t == 0) rowptr[0] = 0;
    }
    grid.sync();

    // phase 5: fill edge_src sorted by dst
    for (int e = gid; e < n_edges; e += gstride) {
        int slot = atomicAdd(&cnt[dst[e]], 1);
        edge_src[slot] = src[e];
    }
}

// ---------------------------------------------------------------------------
// hn[i] = bf16( (sum_nbrs hb[j] + hb[i]) / (deg+1) ).  128-dim bf16 in/out.
__global__ __launch_bounds__(256) void aggregate_kernel(
    const ushort* __restrict__ hb, const int* __restrict__ rowptr,
    const int* __restrict__ edge_src, ushort* __restrict__ hn, int n_nodes) {
    int t = threadIdx.x;
    int g = t & 31;
    int node = blockIdx.x * 8 + (t >> 5);
    if (node >= n_nodes) return;
    const ushort4* h4 = reinterpret_cast<const ushort4*>(hb);
    int e0 = rowptr[node], e1 = rowptr[node + 1];
    ushort4 sv = h4[(size_t)node * 32 + g];  // self term
    float a0x = bf2f(sv.x), a0y = bf2f(sv.y), a0z = bf2f(sv.z), a0w = bf2f(sv.w);
    float a1x = 0.f, a1y = 0.f, a1z = 0.f, a1w = 0.f;
    float a2x = 0.f, a2y = 0.f, a2z = 0.f, a2w = 0.f;
    float a3x = 0.f, a3y = 0.f, a3z = 0.f, a3w = 0.f;
    for (int base = e0; base < e1; base += 32) {
        int m = min(32, e1 - base);
        int sg = (base + g < e1) ? edge_src[base + g] : 0;
        int j = 0;
        for (; j + 4 <= m; j += 4) {
            int s0 = __shfl(sg, j, 32);
            int s1 = __shfl(sg, j + 1, 32);
            int s2 = __shfl(sg, j + 2, 32);
            int s3 = __shfl(sg, j + 3, 32);
            ushort4 v0 = h4[(size_t)s0 * 32 + g];
            ushort4 v1 = h4[(size_t)s1 * 32 + g];
            ushort4 v2 = h4[(size_t)s2 * 32 + g];
            ushort4 v3 = h4[(size_t)s3 * 32 + g];
            a0x += bf2f(v0.x); a0y += bf2f(v0.y); a0z += bf2f(v0.z); a0w += bf2f(v0.w);
            a1x += bf2f(v1.x); a1y += bf2f(v1.y); a1z += bf2f(v1.z); a1w += bf2f(v1.w);
            a2x += bf2f(v2.x); a2y += bf2f(v2.y); a2z += bf2f(v2.z); a2w += bf2f(v2.w);
            a3x += bf2f(v3.x); a3y += bf2f(v3.y); a3z += bf2f(v3.z); a3w += bf2f(v3.w);
        }
        for (; j < m; ++j) {
            int s = __shfl(sg, j, 32);
            ushort4 v = h4[(size_t)s * 32 + g];
            a0x += bf2f(v.x); a0y += bf2f(v.y); a0z += bf2f(v.z); a0w += bf2f(v.w);
        }
    }
    float inv = 1.0f / (float)(e1 - e0 + 1);
    ushort4 o;
    o.x = f2bf((a0x + a1x + a2x + a3x) * inv);
    o.y = f2bf((a0y + a1y + a2y + a3y) * inv);
    o.z = f2bf((a0z + a1z + a2z + a3z) * inv);
    o.w = f2bf((a0w + a1w + a2w + a3w) * inv);
    reinterpret_cast<ushort4*>(hn)[(size_t)node * 32 + g] = o;
}

// ---------------------------------------------------------------------------
// out[i] = (sum_nbrs y[j] + y[i]) / (deg+1) + b.   64-dim bf16 in, fp32 out.
__global__ __launch_bounds__(256) void aggregate64_kernel(
    const ushort* __restrict__ y, const int* __restrict__ rowptr,
    const int* __restrict__ edge_src, const float* __restrict__ b,
    float* __restrict__ out, int n_nodes) {
    int t = threadIdx.x;
    int g = t & 15;
    int node = blockIdx.x * 16 + (t >> 4);
    if (node >= n_nodes) return;
    const ushort4* y4 = reinterpret_cast<const ushort4*>(y);
    int e0 = rowptr[node], e1 = rowptr[node + 1];
    ushort4 sv = y4[(size_t)node * 16 + g];  // self term
    float a0x = bf2f(sv.x), a0y = bf2f(sv.y), a0z = bf2f(sv.z), a0w = bf2f(sv.w);
    float a1x = 0.f, a1y = 0.f, a1z = 0.f, a1w = 0.f;
    float a2x = 0.f, a2y = 0.f, a2z = 0.f, a2w = 0.f;
    float a3x = 0.f, a3y = 0.f, a3z = 0.f, a3w = 0.f;
    for (int base = e0; base < e1; base += 16) {
        int m = min(16, e1 - base);
        int sg = (base + g < e1) ? edge_src[base + g] : 0;
        int j = 0;
        for (; j + 4 <= m; j += 4) {
            int s0 = __shfl(sg, j, 16);
            int s1 = __shfl(sg, j + 1, 16);
            int s2 = __shfl(sg, j + 2, 16);
            int s3 = __shfl(sg, j + 3, 16);
            ushort4 v0 = y4[(size_t)s0 * 16 + g];
            ushort4 v1 = y4[(size_t)s1 * 16 + g];
            ushort4 v2 = y4[(size_t)s2 * 16 + g];
            ushort4 v3 = y4[(size_t)s3 * 16 + g];
            a0x += bf2f(v0.x); a0y += bf2f(v0.y); a0z += bf2f(v0.z); a0w += bf2f(v0.w);
            a1x += bf2f(v1.x); a1y += bf2f(v1.y); a1z += bf2f(v1.z); a1w += bf2f(v1.w);
            a2x += bf2f(v2.x); a2y += bf2f(v2.y); a2z += bf2f(v2.z); a2w += bf2f(v2.w);
            a3x += bf2f(v3.x); a3y += bf2f(v3.y); a3z += bf2f(v3.z); a3w += bf2f(v3.w);
        }
        for (; j < m; ++j) {
            int s = __shfl(sg, j, 16);
            ushort4 v = y4[(size_t)s * 16 + g];
            a0x += bf2f(v.x); a0y += bf2f(v.y); a0z += bf2f(v.z); a0w += bf2f(v.w);
        }
    }
    float inv = 1.0f / (float)(e1 - e0 + 1);
    float4 bv = reinterpret_cast<const float4*>(b)[g];
    float4 o;
    o.x = (a0x + a1x + a2x + a3x) * inv + bv.x;
    o.y = (a0y + a1y + a2y + a3y) * inv + bv.y;
    o.z = (a0z + a1z + a2z + a3z) * inv + bv.z;
    o.w = (a0w + a1w + a2w + a3w) * inv + bv.w;
    reinterpret_cast<float4*>(out)[(size_t)node * 16 + g] = o;
}

// ---------------------------------------------------------------------------
// Fused double GEMM: h = relu(A @ W1 + b1); y = h @ W2.  All bf16 in/out,
// fp32 MFMA accum.  A:[n][128], W1t:[128][128], W2t:[64][128] (n-major).
// 256 thr = 4 waves, BM=64.  h round-trips through As (LDS) as bf16.
// Frag: m/n = lane&15, k = 8*(lane>>4)+i.  C/D: col=lane&15, row=4*(lane>>4)+i.
__global__ __launch_bounds__(256) void gemm12_kernel(
    const ushort* __restrict__ A, const ushort* __restrict__ W1t,
    const float* __restrict__ b1, const ushort* __restrict__ W2t,
    ushort* __restrict__ y, int n_nodes) {
    __shared__ ushort As[64][136];
    __shared__ ushort Ws1[128][136];
    __shared__ ushort Ws2[64][136];

    int t = threadIdx.x;
    int row0 = blockIdx.x * 64;
    for (int i = t; i < 64 * 16; i += 256) {       // stage A
        int r = i >> 4, c = i & 15;
        int gr = row0 + r;
        short8 v = {};
        if (gr < n_nodes)
            v = *reinterpret_cast<const short8*>(&A[(size_t)gr * NF + c * 8]);
        *reinterpret_cast<short8*>(&As[r][c * 8]) = v;
    }
    for (int i = t; i < 128 * 16; i += 256) {      // stage W1t
        int r = i >> 4, c = i & 15;
        *reinterpret_cast<short8*>(&Ws1[r][c * 8]) =
            *reinterpret_cast<const short8*>(&W1t[r * NF + c * 8]);
    }
    for (int i = t; i < 64 * 16; i += 256) {       // stage W2t
        int r = i >> 4, c = i & 15;
        *reinterpret_cast<short8*>(&Ws2[r][c * 8]) =
            *reinterpret_cast<const short8*>(&W2t[r * NF + c * 8]);
    }
    __syncthreads();

    int w = t >> 6;
    int l = t & 63;
    int m16 = l & 15;
    int g = l >> 4;
    int m0 = w * 16;

    // GEMM 1: acc1[nt] = A-tile @ W1 (8 col-tiles)
    f32x4 acc1[8];
#pragma unroll
    for (int nt = 0; nt < 8; nt++) acc1[nt] = {0.f, 0.f, 0.f, 0.f};
#pragma unroll
    for (int kk = 0; kk < 4; kk++) {
        int k0 = kk * 32 + g * 8;
        short8 a = *reinterpret_cast<const short8*>(&As[m0 + m16][k0]);
#pragma unroll
        for (int nt = 0; nt < 8; nt++) {
            short8 b = *reinterpret_cast<const short8*>(&Ws1[nt * 16 + m16][k0]);
            acc1[nt] = __builtin_amdgcn_mfma_f32_16x16x32_bf16(a, b, acc1[nt], 0, 0, 0);
        }
    }
    __syncthreads();   // all As reads done; reuse As for h

    // bias + relu + bf16, write h into As (each wave owns rows m0..m0+15)
#pragma unroll
    for (int nt = 0; nt < 8; nt++) {
        int col = nt * 16 + m16;
        float bv = b1[col];
#pragma unroll
        for (int i = 0; i < 4; i++) {
            int r = m0 + g * 4 + i;
            As[r][col] = f2bf(fmaxf(acc1[nt][i] + bv, 0.f));
        }
    }
    __syncthreads();

    // GEMM 2: y-tile = h @ W2 (4 col-tiles)
    f32x4 acc2[4];
#pragma unroll
    for (int nt = 0; nt < 4; nt++) acc2[nt] = {0.f, 0.f, 0.f, 0.f};
#pragma unroll
    for (int kk = 0; kk < 4; kk++) {
        int k0 = kk * 32 + g * 8;
        short8 a = *reinterpret_cast<const short8*>(&As[m0 + m16][k0]);
#pragma unroll
        for (int nt = 0; nt < 4; nt++) {
            short8 b = *reinterpret_cast<const short8*>(&Ws2[nt * 16 + m16][k0]);
            acc2[nt] = __builtin_amdgcn_mfma_f32_16x16x32_bf16(a, b, acc2[nt], 0, 0, 0);
        }
    }

#pragma unroll
    for (int nt = 0; nt < 4; nt++) {
        int col = nt * 16 + m16;
#pragma unroll
        for (int i = 0; i < 4; i++) {
            int gr = row0 + m0 + g * 4 + i;
            if (gr < n_nodes)
                y[(size_t)gr * 64 + col] = f2bf(acc2[nt][i]);
        }
    }
}

// ---------------------------------------------------------------------------
extern "C" void kernel_launch(void* const* d_in, const int* in_sizes, int n_in,
                              void* d_out, int out_size, void* d_ws, size_t ws_size,
                              hipStream_t stream) {
    const float* x   = (const float*)d_in[0];
    const int*   src = (const int*)d_in[1];
    const int*   dst = (const int*)d_in[2];
    const float* W1  = (const float*)d_in[3];
    const float* b1  = (const float*)d_in[4];
    const float* W2  = (const float*)d_in[5];
    const float* b2  = (const float*)d_in[6];
    float* out = (float*)d_out;

    int n_nodes = in_sizes[0] / NF;   // 50000
    int n_edges = in_sizes[1];        // 600000
    int nb = (n_nodes + 255) / 256;   // 196 (<= 256)
    int n8 = n_nodes * NF / 8;

    // ws: rowptr | cnt | edge_src | partials[256] | W1t | W2t | xb | hn | y
    int* rowptr   = (int*)d_ws;
    int* cnt      = rowptr + (n_nodes + 4);
    int* edge_src = cnt + n_nodes;
    int* partials = edge_src + n_edges;
    size_t iw = (size_t)(n_nodes + 4) + n_nodes + n_edges + 256;
    iw = (iw + 63) & ~(size_t)63;  // 256B align
    ushort* W1t = (ushort*)((int*)d_ws + iw);
    ushort* W2t = W1t + 128 * NF;
    ushort* xb  = W2t + 64 * NF;
    ushort* hn  = xb + (size_t)n_nodes * NF;
    ushort* y   = hn + (size_t)n_nodes * NF;

    {
        void* args[] = {&src, &dst, &cnt, &rowptr, &partials, &edge_src,
                        &x, &W1, &W2, &xb, &W1t, &W2t,
                        &n_nodes, &n_edges, &nb, &n8};
        hipLaunchCooperativeKernel((void*)csr_build_kernel, dim3(1024), dim3(256),
                                   args, 0, stream);
    }

    int ab = (n_nodes + 7) / 8;
    int gb = (n_nodes + 63) / 64;

    aggregate_kernel<<<ab, 256, 0, stream>>>(xb, rowptr, edge_src, hn, n_nodes);
    gemm12_kernel<<<gb, 256, 0, stream>>>(hn, W1t, b1, W2t, y, n_nodes);
    aggregate64_kernel<<<(n_nodes + 15) / 16, 256, 0, stream>>>(y, rowptr, edge_src, b2, out, n_nodes);
}

// Round 10
// 131.473 us; speedup vs baseline: 4.9145x; 4.9145x over previous
//
#include <hip/hip_runtime.h>

#define NF 128

typedef __attribute__((ext_vector_type(8))) short short8;
typedef __attribute__((ext_vector_type(4))) float f32x4;

__device__ inline ushort f2bf(float f) {
    uint u = __float_as_uint(f);
    return (ushort)((u + 0x7FFFu + ((u >> 16) & 1u)) >> 16);  // RNE
}
__device__ inline float bf2f(ushort u) {
    return __uint_as_float(((uint)u) << 16);
}

// ---------------------------------------------------------------------------
// Fused prep: zero cnt + convert W1/W2 (transposed) and x to bf16.
// Pure grid-stride streaming, no sync needed between the pieces.
__global__ __launch_bounds__(256) void prep_kernel(
    const float* __restrict__ x, const float* __restrict__ W1,
    const float* __restrict__ W2, int* __restrict__ cnt,
    ushort* __restrict__ xb, ushort* __restrict__ W1t, ushort* __restrict__ W2t,
    int n_nodes, int n8) {
    int gid = blockIdx.x * 256 + threadIdx.x;
    int gstride = gridDim.x * 256;
    for (int i = gid; i < n_nodes; i += gstride) cnt[i] = 0;
    for (int i = gid; i < 128 * 128; i += gstride) {
        int k = i >> 7, n = i & 127;
        W1t[n * NF + k] = f2bf(W1[i]);
    }
    for (int i = gid; i < 128 * 64; i += gstride) {
        int k = i >> 6, n = i & 63;
        W2t[n * NF + k] = f2bf(W2[i]);
    }
    const float4* in4 = reinterpret_cast<const float4*>(x);
    for (int i = gid; i < n8; i += gstride) {
        float4 v0 = in4[i * 2], v1 = in4[i * 2 + 1];
        short8 o;
        o[0] = (short)f2bf(v0.x); o[1] = (short)f2bf(v0.y);
        o[2] = (short)f2bf(v0.z); o[3] = (short)f2bf(v0.w);
        o[4] = (short)f2bf(v1.x); o[5] = (short)f2bf(v1.y);
        o[6] = (short)f2bf(v1.z); o[7] = (short)f2bf(v1.w);
        *reinterpret_cast<short8*>(&xb[i * 8]) = o;
    }
}

// ---------------------------------------------------------------------------
// cnt[dst[e]] += 1
__global__ void hist_kernel(const int* __restrict__ dst, int* __restrict__ cnt,
                            int n_edges) {
    int i = blockIdx.x * blockDim.x + threadIdx.x;
    if (i < n_edges) atomicAdd(&cnt[dst[i]], 1);
}

// ---------------------------------------------------------------------------
// partials[b] = sum(cnt[b*256 : (b+1)*256])
__global__ __launch_bounds__(256) void reduce_kernel(const int* __restrict__ cnt,
                                                     int* __restrict__ partials,
                                                     int n) {
    __shared__ int s[256];
    int t = threadIdx.x;
    int i = blockIdx.x * 256 + t;
    s[t] = (i < n) ? cnt[i] : 0;
    __syncthreads();
    for (int off = 128; off > 0; off >>= 1) {
        if (t < off) s[t] += s[t + off];
        __syncthreads();
    }
    if (t == 0) partials[blockIdx.x] = s[0];
}

// ---------------------------------------------------------------------------
// Fused: off0 = sum(partials[0..bid)) by block reduction (nb <= 256), then
// block-local scan.  rowptr[i+1]=incl prefix; cnt[i]=excl prefix (cursor).
__global__ __launch_bounds__(256) void scan_apply_kernel(int* __restrict__ cnt,
                                                         int* __restrict__ rowptr,
                                                         const int* __restrict__ partials,
                                                         int n) {
    __shared__ int s[256];
    __shared__ int off0_sh;
    int t = threadIdx.x;
    // off0 = sum of partials below this block
    s[t] = (t < (int)blockIdx.x) ? partials[t] : 0;
    __syncthreads();
    for (int off = 128; off > 0; off >>= 1) {
        if (t < off) s[t] += s[t + off];
        __syncthreads();
    }
    if (t == 0) off0_sh = s[0];
    __syncthreads();
    int off0 = off0_sh;
    __syncthreads();
    // block-local inclusive scan of this chunk
    int i = blockIdx.x * 256 + t;
    int v = (i < n) ? cnt[i] : 0;
    s[t] = v;
    __syncthreads();
    for (int off = 1; off < 256; off <<= 1) {
        int a = (t >= off) ? s[t - off] : 0;
        __syncthreads();
        s[t] += a;
        __syncthreads();
    }
    if (i < n) {
        rowptr[i + 1] = off0 + s[t];
        cnt[i] = off0 + s[t] - v;
    }
    if (blockIdx.x == 0 && t == 0) rowptr[0] = 0;
}

// ---------------------------------------------------------------------------
// edge_src[cursor[dst[e]]++] = src[e]
__global__ void fill_kernel(const int* __restrict__ src,
                            const int* __restrict__ dst,
                            int* __restrict__ cursor,
                            int* __restrict__ edge_src, int n_edges) {
    int i = blockIdx.x * blockDim.x + threadIdx.x;
    if (i < n_edges) {
        int slot = atomicAdd(&cursor[dst[i]], 1);
        edge_src[slot] = src[i];
    }
}

// ---------------------------------------------------------------------------
// hn[i] = bf16( (sum_nbrs hb[j] + hb[i]) / (deg+1) ).  128-dim bf16 in/out.
__global__ __launch_bounds__(256) void aggregate_kernel(
    const ushort* __restrict__ hb, const int* __restrict__ rowptr,
    const int* __restrict__ edge_src, ushort* __restrict__ hn, int n_nodes) {
    int t = threadIdx.x;
    int g = t & 31;
    int node = blockIdx.x * 8 + (t >> 5);
    if (node >= n_nodes) return;
    const ushort4* h4 = reinterpret_cast<const ushort4*>(hb);
    int e0 = rowptr[node], e1 = rowptr[node + 1];
    ushort4 sv = h4[(size_t)node * 32 + g];  // self term
    float a0x = bf2f(sv.x), a0y = bf2f(sv.y), a0z = bf2f(sv.z), a0w = bf2f(sv.w);
    float a1x = 0.f, a1y = 0.f, a1z = 0.f, a1w = 0.f;
    float a2x = 0.f, a2y = 0.f, a2z = 0.f, a2w = 0.f;
    float a3x = 0.f, a3y = 0.f, a3z = 0.f, a3w = 0.f;
    for (int base = e0; base < e1; base += 32) {
        int m = min(32, e1 - base);
        int sg = (base + g < e1) ? edge_src[base + g] : 0;
        int j = 0;
        for (; j + 4 <= m; j += 4) {
            int s0 = __shfl(sg, j, 32);
            int s1 = __shfl(sg, j + 1, 32);
            int s2 = __shfl(sg, j + 2, 32);
            int s3 = __shfl(sg, j + 3, 32);
            ushort4 v0 = h4[(size_t)s0 * 32 + g];
            ushort4 v1 = h4[(size_t)s1 * 32 + g];
            ushort4 v2 = h4[(size_t)s2 * 32 + g];
            ushort4 v3 = h4[(size_t)s3 * 32 + g];
            a0x += bf2f(v0.x); a0y += bf2f(v0.y); a0z += bf2f(v0.z); a0w += bf2f(v0.w);
            a1x += bf2f(v1.x); a1y += bf2f(v1.y); a1z += bf2f(v1.z); a1w += bf2f(v1.w);
            a2x += bf2f(v2.x); a2y += bf2f(v2.y); a2z += bf2f(v2.z); a2w += bf2f(v2.w);
            a3x += bf2f(v3.x); a3y += bf2f(v3.y); a3z += bf2f(v3.z); a3w += bf2f(v3.w);
        }
        for (; j < m; ++j) {
            int s = __shfl(sg, j, 32);
            ushort4 v = h4[(size_t)s * 32 + g];
            a0x += bf2f(v.x); a0y += bf2f(v.y); a0z += bf2f(v.z); a0w += bf2f(v.w);
        }
    }
    float inv = 1.0f / (float)(e1 - e0 + 1);
    ushort4 o;
    o.x = f2bf((a0x + a1x + a2x + a3x) * inv);
    o.y = f2bf((a0y + a1y + a2y + a3y) * inv);
    o.z = f2bf((a0z + a1z + a2z + a3z) * inv);
    o.w = f2bf((a0w + a1w + a2w + a3w) * inv);
    reinterpret_cast<ushort4*>(hn)[(size_t)node * 32 + g] = o;
}

// ---------------------------------------------------------------------------
// out[i] = (sum_nbrs y[j] + y[i]) / (deg+1) + b.   64-dim bf16 in, fp32 out.
__global__ __launch_bounds__(256) void aggregate64_kernel(
    const ushort* __restrict__ y, const int* __restrict__ rowptr,
    const int* __restrict__ edge_src, const float* __restrict__ b,
    float* __restrict__ out, int n_nodes) {
    int t = threadIdx.x;
    int g = t & 15;
    int node = blockIdx.x * 16 + (t >> 4);
    if (node >= n_nodes) return;
    const ushort4* y4 = reinterpret_cast<const ushort4*>(y);
    int e0 = rowptr[node], e1 = rowptr[node + 1];
    ushort4 sv = y4[(size_t)node * 16 + g];  // self term
    float a0x = bf2f(sv.x), a0y = bf2f(sv.y), a0z = bf2f(sv.z), a0w = bf2f(sv.w);
    float a1x = 0.f, a1y = 0.f, a1z = 0.f, a1w = 0.f;
    float a2x = 0.f, a2y = 0.f, a2z = 0.f, a2w = 0.f;
    float a3x = 0.f, a3y = 0.f, a3z = 0.f, a3w = 0.f;
    for (int base = e0; base < e1; base += 16) {
        int m = min(16, e1 - base);
        int sg = (base + g < e1) ? edge_src[base + g] : 0;
        int j = 0;
        for (; j + 4 <= m; j += 4) {
            int s0 = __shfl(sg, j, 16);
            int s1 = __shfl(sg, j + 1, 16);
            int s2 = __shfl(sg, j + 2, 16);
            int s3 = __shfl(sg, j + 3, 16);
            ushort4 v0 = y4[(size_t)s0 * 16 + g];
            ushort4 v1 = y4[(size_t)s1 * 16 + g];
            ushort4 v2 = y4[(size_t)s2 * 16 + g];
            ushort4 v3 = y4[(size_t)s3 * 16 + g];
            a0x += bf2f(v0.x); a0y += bf2f(v0.y); a0z += bf2f(v0.z); a0w += bf2f(v0.w);
            a1x += bf2f(v1.x); a1y += bf2f(v1.y); a1z += bf2f(v1.z); a1w += bf2f(v1.w);
            a2x += bf2f(v2.x); a2y += bf2f(v2.y); a2z += bf2f(v2.z); a2w += bf2f(v2.w);
            a3x += bf2f(v3.x); a3y += bf2f(v3.y); a3z += bf2f(v3.z); a3w += bf2f(v3.w);
        }
        for (; j < m; ++j) {
            int s = __shfl(sg, j, 16);
            ushort4 v = y4[(size_t)s * 16 + g];
            a0x += bf2f(v.x); a0y += bf2f(v.y); a0z += bf2f(v.z); a0w += bf2f(v.w);
        }
    }
    float inv = 1.0f / (float)(e1 - e0 + 1);
    float4 bv = reinterpret_cast<const float4*>(b)[g];
    float4 o;
    o.x = (a0x + a1x + a2x + a3x) * inv + bv.x;
    o.y = (a0y + a1y + a2y + a3y) * inv + bv.y;
    o.z = (a0z + a1z + a2z + a3z) * inv + bv.z;
    o.w = (a0w + a1w + a2w + a3w) * inv + bv.w;
    reinterpret_cast<float4*>(out)[(size_t)node * 16 + g] = o;
}

// ---------------------------------------------------------------------------
// Fused double GEMM: h = relu(A @ W1 + b1); y = h @ W2.  All bf16 in/out,
// fp32 MFMA accum.  A:[n][128], W1t:[128][128], W2t:[64][128] (n-major).
// 256 thr = 4 waves, BM=64.  h round-trips through As (LDS) as bf16.
// Frag: m/n = lane&15, k = 8*(lane>>4)+i.  C/D: col=lane&15, row=4*(lane>>4)+i.
__global__ __launch_bounds__(256) void gemm12_kernel(
    const ushort* __restrict__ A, const ushort* __restrict__ W1t,
    const float* __restrict__ b1, const ushort* __restrict__ W2t,
    ushort* __restrict__ y, int n_nodes) {
    __shared__ ushort As[64][136];
    __shared__ ushort Ws1[128][136];
    __shared__ ushort Ws2[64][136];

    int t = threadIdx.x;
    int row0 = blockIdx.x * 64;
    for (int i = t; i < 64 * 16; i += 256) {       // stage A
        int r = i >> 4, c = i & 15;
        int gr = row0 + r;
        short8 v = {};
        if (gr < n_nodes)
            v = *reinterpret_cast<const short8*>(&A[(size_t)gr * NF + c * 8]);
        *reinterpret_cast<short8*>(&As[r][c * 8]) = v;
    }
    for (int i = t; i < 128 * 16; i += 256) {      // stage W1t
        int r = i >> 4, c = i & 15;
        *reinterpret_cast<short8*>(&Ws1[r][c * 8]) =
            *reinterpret_cast<const short8*>(&W1t[r * NF + c * 8]);
    }
    for (int i = t; i < 64 * 16; i += 256) {       // stage W2t
        int r = i >> 4, c = i & 15;
        *reinterpret_cast<short8*>(&Ws2[r][c * 8]) =
            *reinterpret_cast<const short8*>(&W2t[r * NF + c * 8]);
    }
    __syncthreads();

    int w = t >> 6;
    int l = t & 63;
    int m16 = l & 15;
    int g = l >> 4;
    int m0 = w * 16;

    // GEMM 1: acc1[nt] = A-tile @ W1 (8 col-tiles)
    f32x4 acc1[8];
#pragma unroll
    for (int nt = 0; nt < 8; nt++) acc1[nt] = {0.f, 0.f, 0.f, 0.f};
#pragma unroll
    for (int kk = 0; kk < 4; kk++) {
        int k0 = kk * 32 + g * 8;
        short8 a = *reinterpret_cast<const short8*>(&As[m0 + m16][k0]);
#pragma unroll
        for (int nt = 0; nt < 8; nt++) {
            short8 b = *reinterpret_cast<const short8*>(&Ws1[nt * 16 + m16][k0]);
            acc1[nt] = __builtin_amdgcn_mfma_f32_16x16x32_bf16(a, b, acc1[nt], 0, 0, 0);
        }
    }
    __syncthreads();   // all As reads done; reuse As for h

    // bias + relu + bf16, write h into As (each wave owns rows m0..m0+15)
#pragma unroll
    for (int nt = 0; nt < 8; nt++) {
        int col = nt * 16 + m16;
        float bv = b1[col];
#pragma unroll
        for (int i = 0; i < 4; i++) {
            int r = m0 + g * 4 + i;
            As[r][col] = f2bf(fmaxf(acc1[nt][i] + bv, 0.f));
        }
    }
    __syncthreads();

    // GEMM 2: y-tile = h @ W2 (4 col-tiles)
    f32x4 acc2[4];
#pragma unroll
    for (int nt = 0; nt < 4; nt++) acc2[nt] = {0.f, 0.f, 0.f, 0.f};
#pragma unroll
    for (int kk = 0; kk < 4; kk++) {
        int k0 = kk * 32 + g * 8;
        short8 a = *reinterpret_cast<const short8*>(&As[m0 + m16][k0]);
#pragma unroll
        for (int nt = 0; nt < 4; nt++) {
            short8 b = *reinterpret_cast<const short8*>(&Ws2[nt * 16 + m16][k0]);
            acc2[nt] = __builtin_amdgcn_mfma_f32_16x16x32_bf16(a, b, acc2[nt], 0, 0, 0);
        }
    }

#pragma unroll
    for (int nt = 0; nt < 4; nt++) {
        int col = nt * 16 + m16;
#pragma unroll
        for (int i = 0; i < 4; i++) {
            int gr = row0 + m0 + g * 4 + i;
            if (gr < n_nodes)
                y[(size_t)gr * 64 + col] = f2bf(acc2[nt][i]);
        }
    }
}

// ---------------------------------------------------------------------------
extern "C" void kernel_launch(void* const* d_in, const int* in_sizes, int n_in,
                              void* d_out, int out_size, void* d_ws, size_t ws_size,
                              hipStream_t stream) {
    const float* x   = (const float*)d_in[0];
    const int*   src = (const int*)d_in[1];
    const int*   dst = (const int*)d_in[2];
    const float* W1  = (const float*)d_in[3];
    const float* b1  = (const float*)d_in[4];
    const float* W2  = (const float*)d_in[5];
    const float* b2  = (const float*)d_in[6];
    float* out = (float*)d_out;

    int n_nodes = in_sizes[0] / NF;   // 50000
    int n_edges = in_sizes[1];        // 600000
    int nb = (n_nodes + 255) / 256;   // 196 (<= 256 required)
    int n8 = n_nodes * NF / 8;

    // ws: rowptr | cnt | edge_src | partials[256] | W1t | W2t | xb | hn | y
    int* rowptr   = (int*)d_ws;
    int* cnt      = rowptr + (n_nodes + 4);
    int* edge_src = cnt + n_nodes;
    int* partials = edge_src + n_edges;
    size_t iw = (size_t)(n_nodes + 4) + n_nodes + n_edges + 256;
    iw = (iw + 63) & ~(size_t)63;  // 256B align
    ushort* W1t = (ushort*)((int*)d_ws + iw);
    ushort* W2t = W1t + 128 * NF;
    ushort* xb  = W2t + 64 * NF;
    ushort* hn  = xb + (size_t)n_nodes * NF;
    ushort* y   = hn + (size_t)n_nodes * NF;

    int eb = (n_edges + 255) / 256;

    prep_kernel<<<1024, 256, 0, stream>>>(x, W1, W2, cnt, xb, W1t, W2t, n_nodes, n8);
    hist_kernel<<<eb, 256, 0, stream>>>(dst, cnt, n_edges);
    reduce_kernel<<<nb, 256, 0, stream>>>(cnt, partials, n_nodes);
    scan_apply_kernel<<<nb, 256, 0, stream>>>(cnt, rowptr, partials, n_nodes);
    fill_kernel<<<eb, 256, 0, stream>>>(src, dst, cnt, edge_src, n_edges);

    int ab = (n_nodes + 7) / 8;
    int gb = (n_nodes + 63) / 64;

    aggregate_kernel<<<ab, 256, 0, stream>>>(xb, rowptr, edge_src, hn, n_nodes);
    gemm12_kernel<<<gb, 256, 0, stream>>>(hn, W1t, b1, W2t, y, n_nodes);
    aggregate64_kernel<<<(n_nodes + 15) / 16, 256, 0, stream>>>(y, rowptr, edge_src, b2, out, n_nodes);
}